// Round 1
// baseline (3725.014 us; speedup 1.0000x reference)
//
#include <hip/hip_runtime.h>
#include <math.h>

#define Bc  32
#define Hc  8
#define LQc 256
#define LVc 1024
#define Dc  512

// ---------------------------------------------------------------------------
// C[m,n] = sum_k A[m,k] * W[n,k]   (both row-major; contraction over last dim)
// 128x128 tile, BK=16, 256 threads, 8x8 per-thread register tile.
// All dims assumed multiples of tile sizes (true for this problem).
// ---------------------------------------------------------------------------
__global__ __launch_bounds__(256) void gemm_nt(const float* __restrict__ A,
                                               const float* __restrict__ W,
                                               float* __restrict__ C,
                                               int M, int N, int K) {
    __shared__ float As[128 * 17];
    __shared__ float Ws_[128 * 17];
    const int bm = blockIdx.y * 128;
    const int bn = blockIdx.x * 128;
    const int tid = threadIdx.x;
    const int tr = tid >> 4;   // 0..15
    const int tc = tid & 15;   // 0..15

    float acc[8][8];
#pragma unroll
    for (int i = 0; i < 8; i++)
#pragma unroll
        for (int j = 0; j < 8; j++) acc[i][j] = 0.f;

    for (int k0 = 0; k0 < K; k0 += 16) {
#pragma unroll
        for (int i = 0; i < 8; i++) {
            int idx = tid + i * 256;          // 0..2047
            int r = idx >> 4, c = idx & 15;   // 128 rows x 16 cols
            As[r * 17 + c]  = A[(size_t)(bm + r) * K + k0 + c];
            Ws_[r * 17 + c] = W[(size_t)(bn + r) * K + k0 + c];
        }
        __syncthreads();
#pragma unroll
        for (int kk = 0; kk < 16; kk++) {
            float a[8], w[8];
#pragma unroll
            for (int i = 0; i < 8; i++) a[i] = As[(tr * 8 + i) * 17 + kk];
#pragma unroll
            for (int j = 0; j < 8; j++) w[j] = Ws_[(tc * 8 + j) * 17 + kk];
#pragma unroll
            for (int i = 0; i < 8; i++)
#pragma unroll
                for (int j = 0; j < 8; j++)
                    acc[i][j] = fmaf(a[i], w[j], acc[i][j]);
        }
        __syncthreads();
    }
#pragma unroll
    for (int i = 0; i < 8; i++)
#pragma unroll
        for (int j = 0; j < 8; j++)
            C[(size_t)(bm + tr * 8 + i) * N + bn + tc * 8 + j] = acc[i][j];
}

// ---------------------------------------------------------------------------
// C[b,q,d] = sum_l Wl[q,l] * X[b,l,d] + bias[q]     (NN gemm per batch)
// 128x128 tile over (q,d), BK=16 over l.
// ---------------------------------------------------------------------------
__global__ __launch_bounds__(256) void lenproj(const float* __restrict__ Wl,
                                               const float* __restrict__ bias,
                                               const float* __restrict__ X,
                                               float* __restrict__ C) {
    __shared__ float Ws_[128 * 17];   // [q][l]
    __shared__ float Xs[16 * 129];    // [l][d]
    const int b  = blockIdx.z;
    const int bq = blockIdx.y * 128;
    const int bd = blockIdx.x * 128;
    const int tid = threadIdx.x;
    const int tr = tid >> 4, tc = tid & 15;
    const float* Xb = X + (size_t)b * LVc * Dc;

    float acc[8][8];
#pragma unroll
    for (int i = 0; i < 8; i++)
#pragma unroll
        for (int j = 0; j < 8; j++) acc[i][j] = 0.f;

    for (int l0 = 0; l0 < LVc; l0 += 16) {
#pragma unroll
        for (int i = 0; i < 8; i++) {
            int idx = tid + i * 256;            // 0..2047
            int r = idx >> 4, c = idx & 15;     // 128 x 16
            Ws_[r * 17 + c] = Wl[(size_t)(bq + r) * LVc + l0 + c];
            int xr = idx >> 7, xc = idx & 127;  // 16 x 128
            Xs[xr * 129 + xc] = Xb[(size_t)(l0 + xr) * Dc + bd + xc];
        }
        __syncthreads();
#pragma unroll
        for (int kk = 0; kk < 16; kk++) {
            float a[8], x[8];
#pragma unroll
            for (int i = 0; i < 8; i++) a[i] = Ws_[(tr * 8 + i) * 17 + kk];
#pragma unroll
            for (int j = 0; j < 8; j++) x[j] = Xs[kk * 129 + tc * 8 + j];
#pragma unroll
            for (int i = 0; i < 8; i++)
#pragma unroll
                for (int j = 0; j < 8; j++)
                    acc[i][j] = fmaf(a[i], x[j], acc[i][j]);
        }
        __syncthreads();
    }
#pragma unroll
    for (int i = 0; i < 8; i++) {
        float bi = bias[bq + tr * 8 + i];
#pragma unroll
        for (int j = 0; j < 8; j++)
            C[((size_t)b * LQc + bq + tr * 8 + i) * Dc + bd + tc * 8 + j] =
                acc[i][j] + bi;
    }
}

// ---------------------------------------------------------------------------
// Fused attention: per block = one (n = b*H+h, 32-row q tile).
//   scores = q_tile @ k1[b]^T / sqrt(D), mask cols >= valid_lens[b] -> -1e6,
//   softmax over 256 cols, out_tile = attn @ v1[b].
// 256 threads: tr = tid/32 (0..7), tc = tid%32.
// ---------------------------------------------------------------------------
__global__ __launch_bounds__(256) void attn_kernel(const float* __restrict__ q,
                                                   const float* __restrict__ k1,
                                                   const float* __restrict__ v1,
                                                   const int* __restrict__ valid_lens,
                                                   float* __restrict__ out) {
    __shared__ float smem[12352];   // 49.4 KB, phase-reused
    const int n  = blockIdx.x;      // 0..B*H-1
    const int qt = blockIdx.y;      // 0..7
    const int b  = n >> 3;          // /H
    const int q0 = qt * 32;
    const int tid = threadIdx.x;
    const int tr = tid >> 5;        // 0..7
    const int tc = tid & 31;        // 0..31
    const int vl = valid_lens[b];

    const float* qn = q  + ((size_t)n * LQc + q0) * Dc;
    const float* kb = k1 + (size_t)b * LQc * Dc;
    const float* vb = v1 + (size_t)b * LQc * Dc;

    float* Qs = smem;               // [32][33]
    float* Ks = smem + 32 * 33;     // [256][33]

    // ---- phase 1: scores = q @ k^T -------------------------------------
    float sc[4][8];
#pragma unroll
    for (int i = 0; i < 4; i++)
#pragma unroll
        for (int j = 0; j < 8; j++) sc[i][j] = 0.f;

    for (int k0 = 0; k0 < Dc; k0 += 32) {
#pragma unroll
        for (int i = 0; i < 4; i++) {           // Q tile 32x32
            int idx = tid + i * 256;
            int r = idx >> 5, c = idx & 31;
            Qs[r * 33 + c] = qn[(size_t)r * Dc + k0 + c];
        }
#pragma unroll
        for (int i = 0; i < 32; i++) {          // K tile 256x32
            int idx = tid + i * 256;
            int r = idx >> 5, c = idx & 31;
            Ks[r * 33 + c] = kb[(size_t)r * Dc + k0 + c];
        }
        __syncthreads();
#pragma unroll
        for (int kk = 0; kk < 32; kk++) {
            float qv[4], kv[8];
#pragma unroll
            for (int i = 0; i < 4; i++) qv[i] = Qs[(tr * 4 + i) * 33 + kk];
#pragma unroll
            for (int j = 0; j < 8; j++) kv[j] = Ks[(tc + j * 32) * 33 + kk];
#pragma unroll
            for (int i = 0; i < 4; i++)
#pragma unroll
                for (int j = 0; j < 8; j++)
                    sc[i][j] = fmaf(qv[i], kv[j], sc[i][j]);
        }
        __syncthreads();
    }

    // ---- phase 2: mask + softmax (rows owned by 32-lane groups) --------
    const float scale = 0.044194173824159216f;  // 1/sqrt(512)
    float pr[4][8];
#pragma unroll
    for (int i = 0; i < 4; i++) {
        float rmax = -3.4e38f;
#pragma unroll
        for (int j = 0; j < 8; j++) {
            int col = tc + j * 32;
            float s = sc[i][j] * scale;
            s = (col < vl) ? s : -1e6f;
            sc[i][j] = s;
            rmax = fmaxf(rmax, s);
        }
#pragma unroll
        for (int m = 16; m >= 1; m >>= 1)
            rmax = fmaxf(rmax, __shfl_xor(rmax, m, 64));
        float rsum = 0.f;
#pragma unroll
        for (int j = 0; j < 8; j++) {
            pr[i][j] = expf(sc[i][j] - rmax);
            rsum += pr[i][j];
        }
#pragma unroll
        for (int m = 16; m >= 1; m >>= 1)
            rsum += __shfl_xor(rsum, m, 64);
        float rinv = 1.0f / rsum;
#pragma unroll
        for (int j = 0; j < 8; j++) pr[i][j] *= rinv;
    }

    float* Ps = smem;               // [32][257]  (aliases Qs/Ks — safe post-sync)
    float* Vs = smem + 32 * 257;    // [32][129]
#pragma unroll
    for (int i = 0; i < 4; i++)
#pragma unroll
        for (int j = 0; j < 8; j++)
            Ps[(tr * 4 + i) * 257 + tc + j * 32] = pr[i][j];
    __syncthreads();

    // ---- phase 3: out = attn @ v, 128-col chunks -----------------------
    for (int d0 = 0; d0 < Dc; d0 += 128) {
        float o[4][4];
#pragma unroll
        for (int i = 0; i < 4; i++)
#pragma unroll
            for (int j = 0; j < 4; j++) o[i][j] = 0.f;

        for (int l0 = 0; l0 < LQc; l0 += 32) {
#pragma unroll
            for (int i = 0; i < 16; i++) {      // V tile 32x128
                int idx = tid + i * 256;
                int r = idx >> 7, c = idx & 127;
                Vs[r * 129 + c] = vb[(size_t)(l0 + r) * Dc + d0 + c];
            }
            __syncthreads();
#pragma unroll
            for (int kk = 0; kk < 32; kk++) {
                float p[4], v[4];
#pragma unroll
                for (int i = 0; i < 4; i++) p[i] = Ps[(tr * 4 + i) * 257 + l0 + kk];
#pragma unroll
                for (int j = 0; j < 4; j++) v[j] = Vs[kk * 129 + tc + j * 32];
#pragma unroll
                for (int i = 0; i < 4; i++)
#pragma unroll
                    for (int j = 0; j < 4; j++)
                        o[i][j] = fmaf(p[i], v[j], o[i][j]);
            }
            __syncthreads();
        }
#pragma unroll
        for (int i = 0; i < 4; i++)
#pragma unroll
            for (int j = 0; j < 4; j++)
                out[((size_t)n * LQc + q0 + tr * 4 + i) * Dc + d0 + tc + j * 32] =
                    o[i][j];
    }
}

// ---------------------------------------------------------------------------
extern "C" void kernel_launch(void* const* d_in, const int* in_sizes, int n_in,
                              void* d_out, int out_size, void* d_ws, size_t ws_size,
                              hipStream_t stream) {
    const float* queries    = (const float*)d_in[0];
    const float* keys       = (const float*)d_in[1];
    const float* values     = (const float*)d_in[2];
    const float* W_q        = (const float*)d_in[3];
    const float* W_k        = (const float*)d_in[4];
    const float* W_v        = (const float*)d_in[5];
    const float* W_o        = (const float*)d_in[6];
    const float* W_len      = (const float*)d_in[7];
    const float* b_len      = (const float*)d_in[8];
    const int*   valid_lens = (const int*)d_in[9];
    float* out = (float*)d_out;

    // workspace layout (fp32): t1 | k1 | v1 | attn_out  = 16+16+16+128 MB
    float* t1       = (float*)d_ws;
    float* k1       = t1 + (size_t)Bc * LQc * Dc;
    float* v1       = k1 + (size_t)Bc * LQc * Dc;
    float* attn_out = v1 + (size_t)Bc * LQc * Dc;
    float* qproj    = out;   // stage q-projection in d_out, overwritten by W_o gemm

    dim3 blk(256);

    // q = queries @ W_q^T            [B*H*LQ, D]
    gemm_nt<<<dim3(Dc / 128, (Bc * Hc * LQc) / 128), blk, 0, stream>>>(
        queries, W_q, qproj, Bc * Hc * LQc, Dc, Dc);

    // k1 = (W_len @ keys + b_len) @ W_k^T     [B, LQ, D]
    lenproj<<<dim3(Dc / 128, LQc / 128, Bc), blk, 0, stream>>>(W_len, b_len, keys, t1);
    gemm_nt<<<dim3(Dc / 128, (Bc * LQc) / 128), blk, 0, stream>>>(
        t1, W_k, k1, Bc * LQc, Dc, Dc);

    // v1 = (W_len @ values + b_len) @ W_v^T   [B, LQ, D]
    lenproj<<<dim3(Dc / 128, LQc / 128, Bc), blk, 0, stream>>>(W_len, b_len, values, t1);
    gemm_nt<<<dim3(Dc / 128, (Bc * LQc) / 128), blk, 0, stream>>>(
        t1, W_v, v1, Bc * LQc, Dc, Dc);

    // attention
    attn_kernel<<<dim3(Bc * Hc, LQc / 32), blk, 0, stream>>>(
        qproj, k1, v1, valid_lens, attn_out);

    // out = attn_out @ W_o^T
    gemm_nt<<<dim3(Dc / 128, (Bc * Hc * LQc) / 128), blk, 0, stream>>>(
        attn_out, W_o, out, Bc * Hc * LQc, Dc, Dc);
}

// Round 3
// 385.978 us; speedup vs baseline: 9.6508x; 9.6508x over previous
//
#include <hip/hip_runtime.h>
#include <math.h>

#define Bc  32
#define Hc  8
#define LQc 256
#define LVc 1024
#define Dc  512

typedef short bf16x8 __attribute__((ext_vector_type(8)));
typedef float f32x4  __attribute__((ext_vector_type(4)));

__device__ __forceinline__ unsigned short f2bf(float x) {   // RNE fp32->bf16
    unsigned u = __builtin_bit_cast(unsigned, x);
    u = (u + 0x7fffu + ((u >> 16) & 1u)) >> 16;
    return (unsigned short)u;
}

__device__ __forceinline__ void gload16(const ushort* g, ushort* l) {
    __builtin_amdgcn_global_load_lds(
        (const __attribute__((address_space(1))) unsigned*)g,
        (__attribute__((address_space(3))) unsigned*)l, 16, 0, 0);
}

// ---------------------------------------------------------------------------
// fp32 -> bf16 elementwise convert (vectorized float4 / ushort4)
// ---------------------------------------------------------------------------
__global__ __launch_bounds__(256) void cvt_bf16(const float* __restrict__ in,
                                                ushort* __restrict__ out, int n4) {
    int i = blockIdx.x * 256 + threadIdx.x;
    const int stride = gridDim.x * 256;
    for (; i < n4; i += stride) {
        float4 v = ((const float4*)in)[i];
        ushort4 o;
        o.x = f2bf(v.x); o.y = f2bf(v.y); o.z = f2bf(v.z); o.w = f2bf(v.w);
        ((ushort4*)out)[i] = o;
    }
}

// ---------------------------------------------------------------------------
// fp32 [b][L][D] -> bf16 [b][D][L] transpose+convert, 32x32 LDS tiles
// ---------------------------------------------------------------------------
__global__ __launch_bounds__(256) void transpose_cvt(const float* __restrict__ in,
                                                     ushort* __restrict__ out,
                                                     int L, int D) {
    __shared__ float t[32][33];
    const int b = blockIdx.z;
    const int l0 = blockIdx.x * 32, d0 = blockIdx.y * 32;
    in  += (size_t)b * L * D;
    out += (size_t)b * L * D;
    const int r = threadIdx.x >> 5, c = threadIdx.x & 31;
#pragma unroll
    for (int i = 0; i < 4; i++)
        t[r + 8 * i][c] = in[(size_t)(l0 + r + 8 * i) * D + d0 + c];
    __syncthreads();
#pragma unroll
    for (int i = 0; i < 4; i++)
        out[(size_t)(d0 + r + 8 * i) * L + l0 + c] = f2bf(t[c][r + 8 * i]);
}

// ---------------------------------------------------------------------------
// C[m,n] = alpha * sum_k A[m,k]*B[n,k] (+ bias[m])      (bf16 in, f32 accum)
// 128x128 tile, BK=32, 4 waves (2x2), 4x4 16x16x32 frags per wave.
// STORE: 0 = f32 row-major, 1 = bf16 row-major, 2 = bf16 transposed with
//        256-row batches: out[(m>>8)][n][m&255]  (for v1^T)
// ---------------------------------------------------------------------------
template <int STORE, bool BIAS>
__global__ __launch_bounds__(256) void gemm_bt(const ushort* __restrict__ A,
                                               const ushort* __restrict__ B,
                                               void* __restrict__ Cv,
                                               const float* __restrict__ bias,
                                               int M, int N, int K, float alpha,
                                               long sA, long sB, long sC) {
    __shared__ ushort As[128 * 32];
    __shared__ ushort Bs[128 * 32];
    const int z = blockIdx.z;
    A += (size_t)z * sA;
    B += (size_t)z * sB;
    float*  Cf = (float*)Cv  + (size_t)z * sC;
    ushort* Ch = (ushort*)Cv + (size_t)z * sC;

    const int bm = blockIdx.y * 128, bn = blockIdx.x * 128;
    const int tid = threadIdx.x;
    const int wave = tid >> 6, l = tid & 63;
    const int wm = (wave >> 1) * 64, wn = (wave & 1) * 64;
    const int l15 = l & 15, lh = l >> 4;

    f32x4 acc[4][4];
#pragma unroll
    for (int m = 0; m < 4; m++)
#pragma unroll
        for (int n = 0; n < 4; n++) acc[m][n] = (f32x4){0.f, 0.f, 0.f, 0.f};

    const int srow = tid >> 2, scol = (tid & 3) * 8;
    ushort* ldsA = As + (wave * 16) * 32;
    ushort* ldsB = Bs + (wave * 16) * 32;
    const ushort* gA = A + (size_t)(bm + srow) * K + scol;
    const ushort* gB = B + (size_t)(bn + srow) * K + scol;

    for (int k0 = 0; k0 < K; k0 += 32) {
        gload16(gA + k0, ldsA);
        gload16(gA + k0 + (size_t)64 * K, ldsA + 64 * 32);
        gload16(gB + k0, ldsB);
        gload16(gB + k0 + (size_t)64 * K, ldsB + 64 * 32);
        __syncthreads();
        bf16x8 af[4], bfr[4];
#pragma unroll
        for (int m = 0; m < 4; m++)
            af[m] = *(const bf16x8*)&As[(wm + m * 16 + l15) * 32 + lh * 8];
#pragma unroll
        for (int n = 0; n < 4; n++)
            bfr[n] = *(const bf16x8*)&Bs[(wn + n * 16 + l15) * 32 + lh * 8];
#pragma unroll
        for (int m = 0; m < 4; m++)
#pragma unroll
            for (int n = 0; n < 4; n++)
                acc[m][n] = __builtin_amdgcn_mfma_f32_16x16x32_bf16(
                    af[m], bfr[n], acc[m][n], 0, 0, 0);
        __syncthreads();
    }

    if constexpr (STORE == 2) {
#pragma unroll
        for (int m = 0; m < 4; m++) {
            const int row0 = bm + wm + m * 16 + lh * 4;
            const int bb = row0 >> 8, q = row0 & 255;
#pragma unroll
            for (int n = 0; n < 4; n++) {
                const int col = bn + wn + n * 16 + l15;
                ushort4 o;
                o.x = f2bf(acc[m][n][0] * alpha);
                o.y = f2bf(acc[m][n][1] * alpha);
                o.z = f2bf(acc[m][n][2] * alpha);
                o.w = f2bf(acc[m][n][3] * alpha);
                *(ushort4*)&Ch[(size_t)bb * N * 256 + (size_t)col * 256 + q] = o;
            }
        }
    } else if constexpr (STORE == 1) {
#pragma unroll
        for (int m = 0; m < 4; m++)
#pragma unroll
            for (int r = 0; r < 4; r++) {
                const int row = bm + wm + m * 16 + lh * 4 + r;
                const float bv = BIAS ? bias[row] : 0.f;
#pragma unroll
                for (int n = 0; n < 4; n++) {
                    const int col = bn + wn + n * 16 + l15;
                    Ch[(size_t)row * N + col] = f2bf(acc[m][n][r] * alpha + bv);
                }
            }
    } else {
#pragma unroll
        for (int m = 0; m < 4; m++)
#pragma unroll
            for (int r = 0; r < 4; r++) {
                const int row = bm + wm + m * 16 + lh * 4 + r;
                const float bv = BIAS ? bias[row] : 0.f;
#pragma unroll
                for (int n = 0; n < 4; n++) {
                    const int col = bn + wn + n * 16 + l15;
                    Cf[(size_t)row * N + col] = acc[m][n][r] * alpha + bv;
                }
            }
    }
}

// ---------------------------------------------------------------------------
// Fused attention, MFMA. Block = (n = b*H+h, 64-row q tile), 4 waves.
// Phase A: scores 64x256 = qb(64xD) @ k1(256xD)^T; wave w owns rows
//          [16w,16w+16): frags 1x16, full score row in-wave.
// Softmax in registers (mask col>=vl, unnormalized P -> LDS bf16, rsum -> LDS).
// Phase B: out = P @ v1  via v1T (NT), 2 chunks of 256 d-cols, waves 1x4.
// q is pre-scaled by 1/sqrt(D) in the q-proj epilogue.
// ---------------------------------------------------------------------------
__global__ __launch_bounds__(256) void attn_mfma(const ushort* __restrict__ qb,
                                                 const ushort* __restrict__ k1,
                                                 const ushort* __restrict__ v1T,
                                                 const int* __restrict__ vlen,
                                                 ushort* __restrict__ aout) {
    __shared__ __align__(16) char pool[50432];
    ushort* Qs = (ushort*)pool;              // [64][32]   4 KB   (phase A)
    ushort* Ks = (ushort*)(pool + 4096);     // [256][32] 16 KB   (phase A)
    ushort* Ps = (ushort*)pool;              // [64][264] 33792 B (phase B)
    ushort* Vs = (ushort*)(pool + 33792);    // [256][32] 16 KB   (phase B)
    float*  rs = (float*)(pool + 50176);     // [64] row sums

    const int n = blockIdx.x, qt = blockIdx.y;
    const int b = n >> 3, q0 = qt * 64;
    const int tid = threadIdx.x, wave = tid >> 6, l = tid & 63;
    const int l15 = l & 15, lh = l >> 4;
    const int vl = vlen[b];

    const ushort* qbase = qb  + ((size_t)n * LQc + q0) * Dc;
    const ushort* kbase = k1  + (size_t)b * LQc * Dc;
    const ushort* vbase = v1T + (size_t)b * LQc * Dc;

    const int srow = tid >> 2, scol = (tid & 3) * 8;
    ushort* ldsQ = Qs + (wave * 16) * 32;
    ushort* ldsK = Ks + (wave * 16) * 32;
    ushort* ldsV = Vs + (wave * 16) * 32;

    // ---- phase A: scores ------------------------------------------------
    f32x4 sacc[16];
#pragma unroll
    for (int fn = 0; fn < 16; fn++) sacc[fn] = (f32x4){0.f, 0.f, 0.f, 0.f};

    for (int k0 = 0; k0 < Dc; k0 += 32) {
        gload16(qbase + (size_t)srow * Dc + k0 + scol, ldsQ);
#pragma unroll
        for (int j = 0; j < 4; j++)
            gload16(kbase + (size_t)(j * 64 + srow) * Dc + k0 + scol,
                    ldsK + j * 64 * 32);
        __syncthreads();
        bf16x8 aq = *(const bf16x8*)&Qs[(wave * 16 + l15) * 32 + lh * 8];
#pragma unroll
        for (int fn = 0; fn < 16; fn++) {
            bf16x8 bk = *(const bf16x8*)&Ks[(fn * 16 + l15) * 32 + lh * 8];
            sacc[fn] = __builtin_amdgcn_mfma_f32_16x16x32_bf16(aq, bk, sacc[fn], 0, 0, 0);
        }
        __syncthreads();
    }

    // ---- softmax (rows wave*16 + lh*4 + r) ------------------------------
#pragma unroll
    for (int r = 0; r < 4; r++) {
        const int rowl = wave * 16 + lh * 4 + r;
        float v[16];
        float rmax = -3.4e38f;
#pragma unroll
        for (int fn = 0; fn < 16; fn++) {
            const int col = fn * 16 + l15;
            float s = sacc[fn][r];
            v[fn] = (col < vl) ? s : -1e6f;
            rmax = fmaxf(rmax, v[fn]);
        }
        rmax = fmaxf(rmax, __shfl_xor(rmax, 1));
        rmax = fmaxf(rmax, __shfl_xor(rmax, 2));
        rmax = fmaxf(rmax, __shfl_xor(rmax, 4));
        rmax = fmaxf(rmax, __shfl_xor(rmax, 8));
        float rsum = 0.f;
#pragma unroll
        for (int fn = 0; fn < 16; fn++) {
            v[fn] = __expf(v[fn] - rmax);
            rsum += v[fn];
        }
        rsum += __shfl_xor(rsum, 1);
        rsum += __shfl_xor(rsum, 2);
        rsum += __shfl_xor(rsum, 4);
        rsum += __shfl_xor(rsum, 8);
#pragma unroll
        for (int fn = 0; fn < 16; fn++)
            Ps[rowl * 264 + fn * 16 + l15] = f2bf(v[fn]);
        if (l15 == 0) rs[rowl] = rsum;
    }
    __syncthreads();

    // ---- phase B: out = P @ V -------------------------------------------
    for (int d0 = 0; d0 < Dc; d0 += 256) {
        f32x4 o[4][4];
#pragma unroll
        for (int m = 0; m < 4; m++)
#pragma unroll
            for (int fn = 0; fn < 4; fn++) o[m][fn] = (f32x4){0.f, 0.f, 0.f, 0.f};

        for (int l0 = 0; l0 < LQc; l0 += 32) {
#pragma unroll
            for (int j = 0; j < 4; j++)
                gload16(vbase + (size_t)(d0 + j * 64 + srow) * LQc + l0 + scol,
                        ldsV + j * 64 * 32);
            __syncthreads();
            bf16x8 pa[4];
#pragma unroll
            for (int m = 0; m < 4; m++)
                pa[m] = *(const bf16x8*)&Ps[(m * 16 + l15) * 264 + l0 + lh * 8];
#pragma unroll
            for (int fn = 0; fn < 4; fn++) {
                bf16x8 vb = *(const bf16x8*)&Vs[(wave * 64 + fn * 16 + l15) * 32 + lh * 8];
#pragma unroll
                for (int m = 0; m < 4; m++)
                    o[m][fn] = __builtin_amdgcn_mfma_f32_16x16x32_bf16(pa[m], vb, o[m][fn], 0, 0, 0);
            }
            __syncthreads();
        }
#pragma unroll
        for (int m = 0; m < 4; m++)
#pragma unroll
            for (int r = 0; r < 4; r++) {
                const int rowl = m * 16 + lh * 4 + r;
                const float rinv = 1.0f / rs[rowl];
#pragma unroll
                for (int fn = 0; fn < 4; fn++) {
                    const int col = d0 + wave * 64 + fn * 16 + l15;
                    aout[((size_t)n * LQc + q0 + rowl) * Dc + col] =
                        f2bf(o[m][fn][r] * rinv);
                }
            }
    }
}

// ---------------------------------------------------------------------------
extern "C" void kernel_launch(void* const* d_in, const int* in_sizes, int n_in,
                              void* d_out, int out_size, void* d_ws, size_t ws_size,
                              hipStream_t stream) {
    const float* queries    = (const float*)d_in[0];
    const float* keys       = (const float*)d_in[1];
    const float* values     = (const float*)d_in[2];
    const float* W_q        = (const float*)d_in[3];
    const float* W_k        = (const float*)d_in[4];
    const float* W_v        = (const float*)d_in[5];
    const float* W_o        = (const float*)d_in[6];
    const float* W_len      = (const float*)d_in[7];
    const float* b_len      = (const float*)d_in[8];
    const int*   valid_lens = (const int*)d_in[9];

    char* ws = (char*)d_ws;
    const size_t MB = 1024 * 1024;
    // layout: qb(64M) | r12(64M: keysT+valsT -> qconv -> attn_out) | weights | t1 | k1 | v1T
    ushort* qb      = (ushort*)ws;                    // 64 MB
    ushort* keysT   = (ushort*)(ws + 64 * MB);        // 32 MB
    ushort* valsT   = (ushort*)(ws + 96 * MB);        // 32 MB
    ushort* qconv   = keysT;                          // aliases keysT+valsT (64 MB)
    ushort* attnout = keysT;                          // aliases same region
    ushort* wq = (ushort*)(ws + 128 * MB);
    ushort* wk = wq + 262144;
    ushort* wv = wk + 262144;
    ushort* wo = wv + 262144;
    ushort* wl = wo + 262144;
    ushort* t1  = wl + 262144;                        // 4 Mi elems (8 MB)
    ushort* k1  = t1 + 4194304;
    ushort* v1T = k1 + 4194304;

    const float alpha_q = 0.044194173824159216f;      // 1/sqrt(512)
    dim3 blk(256);

    // convert weights
    cvt_bf16<<<256, blk, 0, stream>>>(W_q,   wq, 65536);
    cvt_bf16<<<256, blk, 0, stream>>>(W_k,   wk, 65536);
    cvt_bf16<<<256, blk, 0, stream>>>(W_v,   wv, 65536);
    cvt_bf16<<<256, blk, 0, stream>>>(W_o,   wo, 65536);
    cvt_bf16<<<256, blk, 0, stream>>>(W_len, wl, 65536);

    // transpose+convert keys/values: [b][1024][512] f32 -> [b][512][1024] bf16
    transpose_cvt<<<dim3(32, 16, 32), blk, 0, stream>>>(keys,   keysT, LVc, Dc);
    transpose_cvt<<<dim3(32, 16, 32), blk, 0, stream>>>(values, valsT, LVc, Dc);

    // k path: t1 = W_len @ keys + b_len ; k1 = t1 @ W_k^T
    gemm_bt<1, true><<<dim3(4, 2, 32), blk, 0, stream>>>(
        wl, keysT, t1, b_len, 256, 512, 1024, 1.f, 0, 524288, 131072);
    gemm_bt<1, false><<<dim3(4, 64, 1), blk, 0, stream>>>(
        t1, wk, k1, nullptr, 8192, 512, 512, 1.f, 0, 0, 0);

    // v path: t1 = W_len @ values + b_len ; v1T = (t1 @ W_v^T)^T per batch
    gemm_bt<1, true><<<dim3(4, 2, 32), blk, 0, stream>>>(
        wl, valsT, t1, b_len, 256, 512, 1024, 1.f, 0, 524288, 131072);
    gemm_bt<2, false><<<dim3(4, 64, 1), blk, 0, stream>>>(
        t1, wv, v1T, nullptr, 8192, 512, 512, 1.f, 0, 0, 0);

    // q path: convert queries, project (scale folded in)
    cvt_bf16<<<2048, blk, 0, stream>>>(queries, qconv, 8388608);
    gemm_bt<1, false><<<dim3(4, 512, 1), blk, 0, stream>>>(
        qconv, wq, qb, nullptr, 65536, 512, 512, alpha_q, 0, 0, 0);

    // attention (overwrites qconv region with attn_out)
    attn_mfma<<<dim3(256, 4), blk, 0, stream>>>(qb, k1, v1T, valid_lens, attnout);

    // output projection -> fp32 d_out
    gemm_bt<0, false><<<dim3(4, 512, 1), blk, 0, stream>>>(
        attnout, wo, d_out, nullptr, 65536, 512, 512, 1.f, 0, 0, 0);
}

// Round 4
// 369.766 us; speedup vs baseline: 10.0740x; 1.0438x over previous
//
#include <hip/hip_runtime.h>
#include <math.h>

#define Bc  32
#define Hc  8
#define LQc 256
#define LVc 1024
#define Dc  512

typedef short bf16x8 __attribute__((ext_vector_type(8)));
typedef float f32x4  __attribute__((ext_vector_type(4)));

__device__ __forceinline__ unsigned short f2bf(float x) {   // RNE fp32->bf16
    unsigned u = __builtin_bit_cast(unsigned, x);
    u = (u + 0x7fffu + ((u >> 16) & 1u)) >> 16;
    return (unsigned short)u;
}

__device__ __forceinline__ void gload16(const ushort* g, ushort* l) {
    __builtin_amdgcn_global_load_lds(
        (const __attribute__((address_space(1))) unsigned*)g,
        (__attribute__((address_space(3))) unsigned*)l, 16, 0, 0);
}

// ---------------------------------------------------------------------------
// fp32 -> bf16 elementwise convert (vectorized float4 / ushort4)
// ---------------------------------------------------------------------------
__global__ __launch_bounds__(256) void cvt_bf16(const float* __restrict__ in,
                                                ushort* __restrict__ out, int n4) {
    int i = blockIdx.x * 256 + threadIdx.x;
    const int stride = gridDim.x * 256;
    for (; i < n4; i += stride) {
        float4 v = ((const float4*)in)[i];
        ushort4 o;
        o.x = f2bf(v.x); o.y = f2bf(v.y); o.z = f2bf(v.z); o.w = f2bf(v.w);
        ((ushort4*)out)[i] = o;
    }
}

// ---------------------------------------------------------------------------
// fp32 [b][L][D] -> bf16 [b][D][L] transpose+convert, 32x32 LDS tiles
// ---------------------------------------------------------------------------
__global__ __launch_bounds__(256) void transpose_cvt(const float* __restrict__ in,
                                                     ushort* __restrict__ out,
                                                     int L, int D) {
    __shared__ float t[32][33];
    const int b = blockIdx.z;
    const int l0 = blockIdx.x * 32, d0 = blockIdx.y * 32;
    in  += (size_t)b * L * D;
    out += (size_t)b * L * D;
    const int r = threadIdx.x >> 5, c = threadIdx.x & 31;
#pragma unroll
    for (int i = 0; i < 4; i++)
        t[r + 8 * i][c] = in[(size_t)(l0 + r + 8 * i) * D + d0 + c];
    __syncthreads();
#pragma unroll
    for (int i = 0; i < 4; i++)
        out[(size_t)(d0 + r + 8 * i) * L + l0 + c] = f2bf(t[c][r + 8 * i]);
}

// ---------------------------------------------------------------------------
// C[m,n] = alpha * sum_k A[m,k]*B[n,k] (+ bias[m])      (bf16 in, f32 accum)
// 128x128 tile, BK=32, 4 waves (2x2), 4x4 16x16x32 frags per wave.
// STORE: 0 = f32 row-major, 1 = bf16 row-major, 2 = bf16 transposed with
//        256-row batches: out[(m>>8)][n][m&255]  (for v1^T)
// SWIZ:  1 = 1D grid, XCD-grouped decode (4 bn-blocks of one bm-panel land on
//        the same XCD; needs gridDim.x = byPerXcd*8*4)
// ---------------------------------------------------------------------------
template <int STORE, bool BIAS, int SWIZ>
__global__ __launch_bounds__(256) void gemm_bt(const ushort* __restrict__ A,
                                               const ushort* __restrict__ B,
                                               void* __restrict__ Cv,
                                               const float* __restrict__ bias,
                                               int M, int N, int K, float alpha,
                                               long sA, long sB, long sC,
                                               int byPerXcd) {
    __shared__ ushort As[128 * 32];
    __shared__ ushort Bs[128 * 32];
    const int z = blockIdx.z;
    A += (size_t)z * sA;
    B += (size_t)z * sB;
    float*  Cf = (float*)Cv  + (size_t)z * sC;
    ushort* Ch = (ushort*)Cv + (size_t)z * sC;

    int bm, bn;
    if constexpr (SWIZ) {
        const int bid = blockIdx.x;
        const int xcd = bid & 7, slot = bid >> 3;
        bm = (xcd * byPerXcd + (slot >> 2)) * 128;
        bn = (slot & 3) * 128;
    } else {
        bm = blockIdx.y * 128;
        bn = blockIdx.x * 128;
    }
    const int tid = threadIdx.x;
    const int wave = tid >> 6, l = tid & 63;
    const int wm = (wave >> 1) * 64, wn = (wave & 1) * 64;
    const int l15 = l & 15, lh = l >> 4;

    f32x4 acc[4][4];
#pragma unroll
    for (int m = 0; m < 4; m++)
#pragma unroll
        for (int n = 0; n < 4; n++) acc[m][n] = (f32x4){0.f, 0.f, 0.f, 0.f};

    const int srow = tid >> 2, scol = (tid & 3) * 8;
    ushort* ldsA = As + (wave * 16) * 32;
    ushort* ldsB = Bs + (wave * 16) * 32;
    const ushort* gA = A + (size_t)(bm + srow) * K + scol;
    const ushort* gB = B + (size_t)(bn + srow) * K + scol;

    for (int k0 = 0; k0 < K; k0 += 32) {
        gload16(gA + k0, ldsA);
        gload16(gA + k0 + (size_t)64 * K, ldsA + 64 * 32);
        gload16(gB + k0, ldsB);
        gload16(gB + k0 + (size_t)64 * K, ldsB + 64 * 32);
        __syncthreads();
        bf16x8 af[4], bfr[4];
#pragma unroll
        for (int m = 0; m < 4; m++)
            af[m] = *(const bf16x8*)&As[(wm + m * 16 + l15) * 32 + lh * 8];
#pragma unroll
        for (int n = 0; n < 4; n++)
            bfr[n] = *(const bf16x8*)&Bs[(wn + n * 16 + l15) * 32 + lh * 8];
#pragma unroll
        for (int m = 0; m < 4; m++)
#pragma unroll
            for (int n = 0; n < 4; n++)
                acc[m][n] = __builtin_amdgcn_mfma_f32_16x16x32_bf16(
                    af[m], bfr[n], acc[m][n], 0, 0, 0);
        __syncthreads();
    }

    if constexpr (STORE == 2) {
#pragma unroll
        for (int m = 0; m < 4; m++) {
            const int row0 = bm + wm + m * 16 + lh * 4;
            const int bb = row0 >> 8, q = row0 & 255;
#pragma unroll
            for (int n = 0; n < 4; n++) {
                const int col = bn + wn + n * 16 + l15;
                ushort4 o;
                o.x = f2bf(acc[m][n][0] * alpha);
                o.y = f2bf(acc[m][n][1] * alpha);
                o.z = f2bf(acc[m][n][2] * alpha);
                o.w = f2bf(acc[m][n][3] * alpha);
                *(ushort4*)&Ch[(size_t)bb * N * 256 + (size_t)col * 256 + q] = o;
            }
        }
    } else if constexpr (STORE == 1) {
#pragma unroll
        for (int m = 0; m < 4; m++)
#pragma unroll
            for (int r = 0; r < 4; r++) {
                const int row = bm + wm + m * 16 + lh * 4 + r;
                const float bv = BIAS ? bias[row] : 0.f;
#pragma unroll
                for (int n = 0; n < 4; n++) {
                    const int col = bn + wn + n * 16 + l15;
                    Ch[(size_t)row * N + col] = f2bf(acc[m][n][r] * alpha + bv);
                }
            }
    } else {
#pragma unroll
        for (int m = 0; m < 4; m++)
#pragma unroll
            for (int r = 0; r < 4; r++) {
                const int row = bm + wm + m * 16 + lh * 4 + r;
                const float bv = BIAS ? bias[row] : 0.f;
#pragma unroll
                for (int n = 0; n < 4; n++) {
                    const int col = bn + wn + n * 16 + l15;
                    Cf[(size_t)row * N + col] = acc[m][n][r] * alpha + bv;
                }
            }
    }
}

// ---------------------------------------------------------------------------
// Fused attention, MFMA, v2. Block = (b, h, q-half): q-tile 128 rows.
// Grid 512 (1D), XCD-decoded so each batch's 16 blocks share one XCD
// (K/V L2-resident). 4 waves.
// Phase A: S(128x256) = q @ K^T; per k0 stage Q 8KB + K 16KB -> 128 wave-MFMA.
//   Wave w owns score rows [32w, 32w+32): 2 row-frags x 16 col-frags.
// Softmax in registers (as before), unnormalized P -> LDS [128][264] bf16
//   (aliases the QK staging region), row sums -> LDS.
// Phase B: out = P @ V via v1T, 4 d-chunks of 128; per l0 stage Vs 8KB
//   -> 64 wave-MFMA. Wave w owns d-cols [32w, 32w+32) within the chunk.
// q pre-scaled by 1/sqrt(D). LDS 76288 B -> 2 blocks/CU.
// ---------------------------------------------------------------------------
__global__ __launch_bounds__(256, 2) void attn_mfma(const ushort* __restrict__ qb,
                                                    const ushort* __restrict__ k1,
                                                    const ushort* __restrict__ v1T,
                                                    const int* __restrict__ vlen,
                                                    ushort* __restrict__ aout) {
    __shared__ __align__(16) char pool[76288];
    ushort* Qs = (ushort*)pool;              // [128][32]  8 KB   (phase A)
    ushort* Ks = (ushort*)(pool + 8192);     // [256][32] 16 KB   (phase A)
    ushort* Ps = (ushort*)pool;              // [128][264] 67584 B (phase B)
    ushort* Vs = (ushort*)(pool + 67584);    // [128][32]  8 KB   (phase B)
    float*  rs = (float*)(pool + 75776);     // [128] row sums

    const int bid = blockIdx.x;
    const int xcd = bid & 7, pos = bid >> 3;      // 64 blocks per XCD
    const int b = xcd * 4 + (pos >> 4);           // 4 batches per XCD
    const int inner = pos & 15;
    const int h = inner >> 1, qh = inner & 1;
    const int n = b * 8 + h;
    const int q0 = qh * 128;

    const int tid = threadIdx.x, wave = tid >> 6, l = tid & 63;
    const int l15 = l & 15, lh = l >> 4;
    const int vl = vlen[b];

    const ushort* qbase = qb  + ((size_t)n * LQc + q0) * Dc;
    const ushort* kbase = k1  + (size_t)b * LQc * Dc;
    const ushort* vbase = v1T + (size_t)b * LQc * Dc;

    const int srow = tid >> 2, scol = (tid & 3) * 8;

    // ---- phase A: scores 128x256 ---------------------------------------
    f32x4 sacc[2][16];
#pragma unroll
    for (int m = 0; m < 2; m++)
#pragma unroll
        for (int fn = 0; fn < 16; fn++) sacc[m][fn] = (f32x4){0.f, 0.f, 0.f, 0.f};

    for (int k0 = 0; k0 < Dc; k0 += 32) {
        gload16(qbase + (size_t)srow * Dc + k0 + scol,        Qs + (wave * 16) * 32);
        gload16(qbase + (size_t)(64 + srow) * Dc + k0 + scol, Qs + (64 + wave * 16) * 32);
#pragma unroll
        for (int j = 0; j < 4; j++)
            gload16(kbase + (size_t)(j * 64 + srow) * Dc + k0 + scol,
                    Ks + (j * 64 + wave * 16) * 32);
        __syncthreads();
        bf16x8 aq[2];
        aq[0] = *(const bf16x8*)&Qs[(wave * 32 + l15) * 32 + lh * 8];
        aq[1] = *(const bf16x8*)&Qs[(wave * 32 + 16 + l15) * 32 + lh * 8];
#pragma unroll
        for (int fn = 0; fn < 16; fn++) {
            bf16x8 bk = *(const bf16x8*)&Ks[(fn * 16 + l15) * 32 + lh * 8];
            sacc[0][fn] = __builtin_amdgcn_mfma_f32_16x16x32_bf16(aq[0], bk, sacc[0][fn], 0, 0, 0);
            sacc[1][fn] = __builtin_amdgcn_mfma_f32_16x16x32_bf16(aq[1], bk, sacc[1][fn], 0, 0, 0);
        }
        __syncthreads();
    }

    // ---- softmax: wave owns rows [32w, 32w+32) --------------------------
#pragma unroll
    for (int m = 0; m < 2; m++)
#pragma unroll
        for (int r = 0; r < 4; r++) {
            const int rowl = wave * 32 + m * 16 + lh * 4 + r;
            float v[16];
            float rmax = -3.4e38f;
#pragma unroll
            for (int fn = 0; fn < 16; fn++) {
                const int col = fn * 16 + l15;
                float s = sacc[m][fn][r];
                v[fn] = (col < vl) ? s : -1e6f;
                rmax = fmaxf(rmax, v[fn]);
            }
            rmax = fmaxf(rmax, __shfl_xor(rmax, 1));
            rmax = fmaxf(rmax, __shfl_xor(rmax, 2));
            rmax = fmaxf(rmax, __shfl_xor(rmax, 4));
            rmax = fmaxf(rmax, __shfl_xor(rmax, 8));
            float rsum = 0.f;
#pragma unroll
            for (int fn = 0; fn < 16; fn++) {
                v[fn] = __expf(v[fn] - rmax);
                rsum += v[fn];
            }
            rsum += __shfl_xor(rsum, 1);
            rsum += __shfl_xor(rsum, 2);
            rsum += __shfl_xor(rsum, 4);
            rsum += __shfl_xor(rsum, 8);
#pragma unroll
            for (int fn = 0; fn < 16; fn++)
                Ps[rowl * 264 + fn * 16 + l15] = f2bf(v[fn]);
            if (l15 == 0) rs[rowl] = rsum;
        }
    __syncthreads();

    // ---- phase B: out = P @ V, 4 chunks of 128 d-cols --------------------
    for (int d0 = 0; d0 < Dc; d0 += 128) {
        f32x4 o[8][2];
#pragma unroll
        for (int qf = 0; qf < 8; qf++)
#pragma unroll
            for (int df = 0; df < 2; df++) o[qf][df] = (f32x4){0.f, 0.f, 0.f, 0.f};

        for (int l0 = 0; l0 < LQc; l0 += 32) {
            gload16(vbase + (size_t)(d0 + srow) * LQc + l0 + scol,      Vs + (wave * 16) * 32);
            gload16(vbase + (size_t)(d0 + 64 + srow) * LQc + l0 + scol, Vs + (64 + wave * 16) * 32);
            __syncthreads();
            bf16x8 vb[2];
            vb[0] = *(const bf16x8*)&Vs[(wave * 32 + l15) * 32 + lh * 8];
            vb[1] = *(const bf16x8*)&Vs[(wave * 32 + 16 + l15) * 32 + lh * 8];
#pragma unroll
            for (int qf = 0; qf < 8; qf++) {
                bf16x8 pa = *(const bf16x8*)&Ps[(qf * 16 + l15) * 264 + l0 + lh * 8];
                o[qf][0] = __builtin_amdgcn_mfma_f32_16x16x32_bf16(pa, vb[0], o[qf][0], 0, 0, 0);
                o[qf][1] = __builtin_amdgcn_mfma_f32_16x16x32_bf16(pa, vb[1], o[qf][1], 0, 0, 0);
            }
            __syncthreads();
        }
#pragma unroll
        for (int qf = 0; qf < 8; qf++)
#pragma unroll
            for (int r = 0; r < 4; r++) {
                const int rowl = qf * 16 + lh * 4 + r;
                const float rinv = 1.0f / rs[rowl];
#pragma unroll
                for (int df = 0; df < 2; df++) {
                    const int col = d0 + wave * 32 + df * 16 + l15;
                    aout[((size_t)n * LQc + q0 + rowl) * Dc + col] =
                        f2bf(o[qf][df][r] * rinv);
                }
            }
    }
}

// ---------------------------------------------------------------------------
extern "C" void kernel_launch(void* const* d_in, const int* in_sizes, int n_in,
                              void* d_out, int out_size, void* d_ws, size_t ws_size,
                              hipStream_t stream) {
    const float* queries    = (const float*)d_in[0];
    const float* keys       = (const float*)d_in[1];
    const float* values     = (const float*)d_in[2];
    const float* W_q        = (const float*)d_in[3];
    const float* W_k        = (const float*)d_in[4];
    const float* W_v        = (const float*)d_in[5];
    const float* W_o        = (const float*)d_in[6];
    const float* W_len      = (const float*)d_in[7];
    const float* b_len      = (const float*)d_in[8];
    const int*   valid_lens = (const int*)d_in[9];

    char* ws = (char*)d_ws;
    const size_t MB = 1024 * 1024;
    // layout: qb(64M) | r12(64M: keysT+valsT -> qconv -> attn_out) | weights | t1 | k1 | v1T
    ushort* qb      = (ushort*)ws;                    // 64 MB
    ushort* keysT   = (ushort*)(ws + 64 * MB);        // 32 MB
    ushort* valsT   = (ushort*)(ws + 96 * MB);        // 32 MB
    ushort* qconv   = keysT;                          // aliases keysT+valsT (64 MB)
    ushort* attnout = keysT;                          // aliases same region
    ushort* wq = (ushort*)(ws + 128 * MB);
    ushort* wk = wq + 262144;
    ushort* wv = wk + 262144;
    ushort* wo = wv + 262144;
    ushort* wl = wo + 262144;
    ushort* t1  = wl + 262144;                        // 4 Mi elems (8 MB)
    ushort* k1  = t1 + 4194304;
    ushort* v1T = k1 + 4194304;

    const float alpha_q = 0.044194173824159216f;      // 1/sqrt(512)
    dim3 blk(256);

    // convert weights
    cvt_bf16<<<256, blk, 0, stream>>>(W_q,   wq, 65536);
    cvt_bf16<<<256, blk, 0, stream>>>(W_k,   wk, 65536);
    cvt_bf16<<<256, blk, 0, stream>>>(W_v,   wv, 65536);
    cvt_bf16<<<256, blk, 0, stream>>>(W_o,   wo, 65536);
    cvt_bf16<<<256, blk, 0, stream>>>(W_len, wl, 65536);

    // transpose+convert keys/values: [b][1024][512] f32 -> [b][512][1024] bf16
    transpose_cvt<<<dim3(32, 16, 32), blk, 0, stream>>>(keys,   keysT, LVc, Dc);
    transpose_cvt<<<dim3(32, 16, 32), blk, 0, stream>>>(values, valsT, LVc, Dc);

    // k path: t1 = W_len @ keys + b_len ; k1 = t1 @ W_k^T
    gemm_bt<1, true, 0><<<dim3(4, 2, 32), blk, 0, stream>>>(
        wl, keysT, t1, b_len, 256, 512, 1024, 1.f, 0, 524288, 131072, 0);
    gemm_bt<1, false, 1><<<dim3(256), blk, 0, stream>>>(
        t1, wk, k1, nullptr, 8192, 512, 512, 1.f, 0, 0, 0, 8);

    // v path: t1 = W_len @ values + b_len ; v1T = (t1 @ W_v^T)^T per batch
    gemm_bt<1, true, 0><<<dim3(4, 2, 32), blk, 0, stream>>>(
        wl, valsT, t1, b_len, 256, 512, 1024, 1.f, 0, 524288, 131072, 0);
    gemm_bt<2, false, 1><<<dim3(256), blk, 0, stream>>>(
        t1, wv, v1T, nullptr, 8192, 512, 512, 1.f, 0, 0, 0, 8);

    // q path: convert queries, project (scale folded in)
    cvt_bf16<<<2048, blk, 0, stream>>>(queries, qconv, 8388608);
    gemm_bt<1, false, 1><<<dim3(2048), blk, 0, stream>>>(
        qconv, wq, qb, nullptr, 65536, 512, 512, alpha_q, 0, 0, 0, 64);

    // attention (overwrites qconv region with attn_out)
    attn_mfma<<<dim3(512), blk, 0, stream>>>(qb, k1, v1T, valid_lens, attnout);

    // output projection -> fp32 d_out
    gemm_bt<0, false, 1><<<dim3(2048), blk, 0, stream>>>(
        attnout, wo, d_out, nullptr, 65536, 512, 512, 1.f, 0, 0, 0, 64);
}